// Round 4
// baseline (62.314 us; speedup 1.0000x reference)
//
#include <hip/hip_runtime.h>

// Problem constants (fixed by reference): S=256, B=64, D=1024, T=64
#define SLEN 256
#define NB   64
#define ND   1024
#define NT   64
// BOS=0, EOS=1, PAD=2

typedef float f32x4  __attribute__((ext_vector_type(4)));
typedef short bf16x8 __attribute__((ext_vector_type(8)));
typedef unsigned int u32;
typedef u32 u32x2 __attribute__((ext_vector_type(2)));
typedef u32 u32x4 __attribute__((ext_vector_type(4)));

__device__ __forceinline__ u32 cvt_pk_bf16(float lo, float hi) {
  u32 r;
  asm("v_cvt_pk_bf16_f32 %0, %1, %2" : "=v"(r) : "v"(lo), "v"(hi));
  return r;
}

__device__ __forceinline__ unsigned short f2bf(float f) {   // RNE, f finite >0
  u32 u = __float_as_uint(f);
  return (unsigned short)((u + 0x7FFFu + ((u >> 16) & 1u)) >> 16);
}

__device__ __forceinline__ bf16x8 pack_bf16x8(f32x4 a, f32x4 b) {
  union { u32 u[4]; bf16x8 v; } r;
  r.u[0] = cvt_pk_bf16(a.x, a.y);
  r.u[1] = cvt_pk_bf16(a.z, a.w);
  r.u[2] = cvt_pk_bf16(b.x, b.y);
  r.u[3] = cvt_pk_bf16(b.z, b.w);
  return r.v;
}

// ---------------------------------------------------------------------------
// Kernel 0: blocks 0..255: W -> bf16 frag-stream (B-frag of 16x16x32).
//           block 256:     E'^T hi/lo A-frag table (16 KB) + zero out[0].
// E-frag element e of lane l (q=l>>4,c=l&15), tile (mt,kf):
//   exp(trans[(32kf+8q+e)*64 + 16mt+c]) * 2^-6, RNE-split into bf16 hi + lo.
// Word layout: Ebuf[((mt*2+kf)*2 + h)*256 + l*4 + w] = pk(elem 2w, elem 2w+1)
// ---------------------------------------------------------------------------
__global__ __launch_bounds__(256) void prep(const float* __restrict__ W,
                                            const float* __restrict__ trans,
                                            unsigned short* __restrict__ Wb3,
                                            u32* __restrict__ Ebuf,
                                            float* __restrict__ out) {
  if (blockIdx.x < 256) {
    int o  = blockIdx.x * 256 + threadIdx.x;          // 0..65535
    int e  = o & 7;
    int l  = (o >> 3) & 63;
    int f  = (o >> 9) & 3;
    int k0 = o >> 11;
    int t  = f * 16 + (l & 15);
    int k  = k0 * 32 + ((l >> 4) << 3) + e;
    Wb3[o] = f2bf(W[t * ND + k]);
    return;
  }
  const int tid = threadIdx.x;
  if (tid == 0) out[0] = 0.f;
  const int l = tid & 63, w = tid >> 6;               // w = word 0..3
  const int q = l >> 4, c = l & 15;
#pragma unroll
  for (int mt = 0; mt < 4; ++mt)
#pragma unroll
    for (int kf = 0; kf < 2; ++kf) {
      float v0 = __expf(trans[(32 * kf + 8 * q + 2 * w)     * NT + 16 * mt + c]) * 0.015625f;
      float v1 = __expf(trans[(32 * kf + 8 * q + 2 * w + 1) * NT + 16 * mt + c]) * 0.015625f;
      u32 u0 = __float_as_uint(v0), u1 = __float_as_uint(v1);
      float h0 = __uint_as_float((u0 + 0x7FFFu + ((u0 >> 16) & 1u)) & 0xFFFF0000u);
      float h1 = __uint_as_float((u1 + 0x7FFFu + ((u1 >> 16) & 1u)) & 0xFFFF0000u);
      Ebuf[((mt * 2 + kf) * 2 + 0) * 256 + l * 4 + w] = cvt_pk_bf16(h0, h1);
      Ebuf[((mt * 2 + kf) * 2 + 1) * 256 + l * 4 + w] = cvt_pk_bf16(v0 - h0, v1 - h1);
    }
}

// ---------------------------------------------------------------------------
// Kernel 1: xbuf[r][t] = bf16( exp( features[r]·W[t] + b[t] ) ), r = s*B+b.
// ---------------------------------------------------------------------------
__global__ __launch_bounds__(256) void emit_gemm(const float* __restrict__ F,
                                                 const unsigned short* __restrict__ Wb3,
                                                 const float* __restrict__ bias,
                                                 unsigned short* __restrict__ xbuf) {
  const int lane = threadIdx.x & 63;
  const int wv   = (blockIdx.x * 256 + threadIdx.x) >> 6;  // 0..1023
  const int r0   = wv * 16;
  const int m    = lane & 15;
  const int kg   = lane >> 4;
  const float* arow = F + (size_t)(r0 + m) * ND + kg * 8;
  const bf16x8* bptr = reinterpret_cast<const bf16x8*>(Wb3) + lane;

  f32x4 acc0 = {0.f, 0.f, 0.f, 0.f};
  f32x4 acc1 = acc0, acc2 = acc0, acc3 = acc0;

  for (int g = 0; g < 32; g += 4) {
    f32x4  a[4][2];
    bf16x8 bb[4][4];
#pragma unroll
    for (int qq = 0; qq < 4; ++qq) {
      a[qq][0] = *(const f32x4*)(arow + (g + qq) * 32);
      a[qq][1] = *(const f32x4*)(arow + (g + qq) * 32 + 4);
#pragma unroll
      for (int f = 0; f < 4; ++f) bb[qq][f] = bptr[((g + qq) * 4 + f) * 64];
    }
#pragma unroll
    for (int qq = 0; qq < 4; ++qq) {
      bf16x8 af = pack_bf16x8(a[qq][0], a[qq][1]);
      acc0 = __builtin_amdgcn_mfma_f32_16x16x32_bf16(af, bb[qq][0], acc0, 0, 0, 0);
      acc1 = __builtin_amdgcn_mfma_f32_16x16x32_bf16(af, bb[qq][1], acc1, 0, 0, 0);
      acc2 = __builtin_amdgcn_mfma_f32_16x16x32_bf16(af, bb[qq][2], acc2, 0, 0, 0);
      acc3 = __builtin_amdgcn_mfma_f32_16x16x32_bf16(af, bb[qq][3], acc3, 0, 0, 0);
    }
  }

  const float bv0 = bias[m], bv1 = bias[16 + m], bv2 = bias[32 + m], bv3 = bias[48 + m];
  unsigned short* op = xbuf + (size_t)(r0 + kg * 4) * NT + m;
#pragma unroll
  for (int r = 0; r < 4; ++r) {
    op[r * NT +  0] = f2bf(__expf(acc0[r] + bv0));
    op[r * NT + 16] = f2bf(__expf(acc1[r] + bv1));
    op[r * NT + 32] = f2bf(__expf(acc2[r] + bv2));
    op[r * NT + 48] = f2bf(__expf(acc3[r] + bv3));
  }
}

// ---------------------------------------------------------------------------
// Kernel 2 (stage A): per-(batch,chunk) product matrix G_k (R3-proven math),
// E-frags loaded from Ebuf, x from bf16 xbuf. Wave 0 also computes this
// chunk's slice of the gold path score and atomicAdds -gold into out.
// ---------------------------------------------------------------------------
__global__ __launch_bounds__(256) void chunk_prod(const unsigned short* __restrict__ xbuf,
                                                  const float* __restrict__ trans,
                                                  const u32*   __restrict__ Ebuf,
                                                  const int*   __restrict__ tags,
                                                  const int*   __restrict__ seq_lens,
                                                  unsigned short* __restrict__ Gout,
                                                  float* __restrict__ out) {
  __shared__ float lds[64 * 68];
  const int b   = blockIdx.x >> 4;
  const int k   = blockIdx.x & 15;
  const int tid = threadIdx.x;
  const int nt  = tid >> 6;           // wave id = column tile
  const int l   = tid & 63;
  const int q   = l >> 4, c = l & 15;

  const int L = seq_lens[b];          // in [2,256]

  // ---- gold slice: s in [16k, 16k+16) ∩ [0, L), wave 0 lanes 0..15 ----
  if (nt == 0) {
    float gp = 0.f;
    int s = 16 * k + (l & 15);
    if (l < 16 && s < L) {
      int tg = tags[s * NB + b];
      int nx = (s + 1 < SLEN) ? tags[(s + 1) * NB + b] : 2;
      float xv = __uint_as_float((u32)xbuf[(size_t)(s * NB + b) * NT + tg] << 16);
      gp = __logf(xv) + trans[tg * NT + nx];
    }
    gp += __shfl_xor(gp, 1, 64);
    gp += __shfl_xor(gp, 2, 64);
    gp += __shfl_xor(gp, 4, 64);
    gp += __shfl_xor(gp, 8, 64);
    if (l == 0) atomicAdd(out, -gp);
  }

  // ---- E'^T fragments from table (hi + lo) ----
  union uf { u32x4 u; bf16x8 v; };
  uf eh[4][2], el[4][2];
#pragma unroll
  for (int mt = 0; mt < 4; ++mt)
#pragma unroll
    for (int kf = 0; kf < 2; ++kf) {
      eh[mt][kf].u = *(const u32x4*)(Ebuf + ((mt * 2 + kf) * 2 + 0) * 256 + l * 4);
      el[mt][kf].u = *(const u32x4*)(Ebuf + ((mt * 2 + kf) * 2 + 1) * 256 + l * 4);
    }

  // ---- G = I (this wave's column tile): G[16mt+4q+r][16nt+c] ----
  f32x4 g[4];
#pragma unroll
  for (int mt = 0; mt < 4; ++mt) {
    f32x4 z = {0.f, 0.f, 0.f, 0.f};
    int r = c - 4 * q;
    if (mt == nt && r >= 0 && r < 4) z[r] = 1.0f;
    g[mt] = z;
  }

  int tbeg = 16 * k; if (tbeg < 1) tbeg = 1;
  int tend = 16 * k + 16; if (tend > L) tend = L;

  const unsigned short* xb = xbuf + (size_t)b * NT + 4 * q;  // + t*4096 + 16*mt

#define SWAPQ(A, B) do {                                                  \
    asm("v_permlane32_swap_b32 %0, %1" : "+v"(A), "+v"(B));               \
    asm("v_permlane16_swap_b32 %0, %1" : "+v"(A), "+v"(B));               \
  } while (0)

  if (tbeg < tend) {
    u32x2 xs[4], xn[4];
#pragma unroll
    for (int mt = 0; mt < 4; ++mt)
      xs[mt] = *(const u32x2*)(xb + (size_t)tbeg * (NB * NT) + 16 * mt);

    for (int t = tbeg; t < tend; ++t) {
#pragma unroll
      for (int mt = 0; mt < 4; ++mt)
        xn[mt] = *(const u32x2*)(xb + (size_t)(t + 1) * (NB * NT) + 16 * mt);

      u32 p[4][2];
#pragma unroll
      for (int mt = 0; mt < 4; ++mt) {
        u32 w0 = xs[mt].x, w1 = xs[mt].y;
        f32x4 xv;
        xv.x = __uint_as_float(w0 << 16);
        xv.y = __uint_as_float(w0 & 0xFFFF0000u);
        xv.z = __uint_as_float(w1 << 16);
        xv.w = __uint_as_float(w1 & 0xFFFF0000u);
        f32x4 ww = g[mt] * xv;                // row-scale by x (rows = src tags)
        p[mt][0] = cvt_pk_bf16(ww.x, ww.y);
        p[mt][1] = cvt_pk_bf16(ww.z, ww.w);
      }
      SWAPQ(p[0][0], p[1][0]); SWAPQ(p[0][1], p[1][1]);
      SWAPQ(p[2][0], p[3][0]); SWAPQ(p[2][1], p[3][1]);
      union { u32 u[4]; bf16x8 v; } B0, B1;
      B0.u[0] = p[0][0]; B0.u[1] = p[0][1]; B0.u[2] = p[1][0]; B0.u[3] = p[1][1];
      B1.u[0] = p[2][0]; B1.u[1] = p[2][1]; B1.u[2] = p[3][0]; B1.u[3] = p[3][1];

      const f32x4 zz = {0.f, 0.f, 0.f, 0.f};
#pragma unroll
      for (int mt = 0; mt < 4; ++mt) {        // hi-chain ∥ lo-chain (2-deep)
        f32x4 dh, dl;
        dh = __builtin_amdgcn_mfma_f32_16x16x32_bf16(eh[mt][0].v, B0.v, zz, 0, 0, 0);
        dh = __builtin_amdgcn_mfma_f32_16x16x32_bf16(eh[mt][1].v, B1.v, dh, 0, 0, 0);
        dl = __builtin_amdgcn_mfma_f32_16x16x32_bf16(el[mt][0].v, B0.v, zz, 0, 0, 0);
        dl = __builtin_amdgcn_mfma_f32_16x16x32_bf16(el[mt][1].v, B1.v, dl, 0, 0, 0);
        g[mt] = dh + dl;
      }
#pragma unroll
      for (int mt = 0; mt < 4; ++mt) xs[mt] = xn[mt];
    }
  }
#undef SWAPQ

  // ---- transpose via LDS, pack bf16, store row-major ----
#pragma unroll
  for (int mt = 0; mt < 4; ++mt)
#pragma unroll
    for (int r = 0; r < 4; ++r)
      lds[(16 * mt + 4 * q + r) * 68 + 16 * nt + c] = g[mt][r];
  __syncthreads();
  {
    int row = tid >> 2, qt = tid & 3;
    const float* src = lds + row * 68 + qt * 16;
    u32 w[8];
#pragma unroll
    for (int m = 0; m < 8; ++m) w[m] = cvt_pk_bf16(src[2 * m], src[2 * m + 1]);
    u32x4* dst = (u32x4*)(Gout + (((size_t)(b * 16 + k) * 64 + row) * 64 + qt * 16));
    dst[0] = *(u32x4*)&w[0];
    dst[1] = *(u32x4*)&w[4];
  }
}

// ---------------------------------------------------------------------------
// Kernel 3 (stage B): per-batch alpha scan through 16 chunk matrices
// (R3-proven), then atomicAdd the batch's logZ contribution into out.
// ---------------------------------------------------------------------------
__global__ __launch_bounds__(64) void chain_apply(const unsigned short* __restrict__ xbuf,
                                                  const float* __restrict__ trans,
                                                  const unsigned short* __restrict__ Gout,
                                                  const int*   __restrict__ seq_lens,
                                                  float* __restrict__ out) {
  __shared__ __align__(16) float elds[64];
  const int b = blockIdx.x;
  const int j = threadIdx.x;
  const int L = seq_lens[b];

  float A    = __expf(trans[j]);                                        // trans[BOS][j]
  float logZ = __logf(__uint_as_float((u32)xbuf[(size_t)b * NT] << 16)); // emit[0,b,BOS]

  const unsigned short* gbase = Gout + (size_t)b * 16 * 4096 + (size_t)j * 64;
  u32x4 gc[8], gn[8];
#pragma unroll
  for (int m = 0; m < 8; ++m) gc[m] = *((const u32x4*)gbase + m);

  const float C6 = 6.f * 0.6931471805599453f;

  for (int k = 0; k < 16; ++k) {
    if (k < 15) {
      const u32x4* gb2 = (const u32x4*)(gbase + (size_t)(k + 1) * 4096);
#pragma unroll
      for (int m = 0; m < 8; ++m) gn[m] = gb2[m];
    }
    int tb = 16 * k; if (tb < 1) tb = 1;
    int te = 16 * k + 16; if (te > L) te = L;
    int n = te - tb;
    if (n > 0) {
      elds[j] = A;                    // same-wave DS ordering (R1-proven)
      float s0 = 0.f, s1 = 0.f, s2 = 0.f, s3 = 0.f;
#pragma unroll
      for (int m = 0; m < 8; ++m) {
        f32x4 av0 = *(const f32x4*)(elds + 8 * m);
        f32x4 av1 = *(const f32x4*)(elds + 8 * m + 4);
        u32x4 w = gc[m];
        s0 = fmaf(av0.x, __uint_as_float(w.x << 16),         s0);
        s1 = fmaf(av0.y, __uint_as_float(w.x & 0xFFFF0000u), s1);
        s2 = fmaf(av0.z, __uint_as_float(w.y << 16),         s2);
        s3 = fmaf(av0.w, __uint_as_float(w.y & 0xFFFF0000u), s3);
        s0 = fmaf(av1.x, __uint_as_float(w.z << 16),         s0);
        s1 = fmaf(av1.y, __uint_as_float(w.z & 0xFFFF0000u), s1);
        s2 = fmaf(av1.z, __uint_as_float(w.w << 16),         s2);
        s3 = fmaf(av1.w, __uint_as_float(w.w & 0xFFFF0000u), s3);
      }
      A = (s0 + s1) + (s2 + s3);
      logZ += C6 * (float)n;
      u32 bb = __builtin_amdgcn_readfirstlane(__float_as_uint(A));
      int ex = (int)((bb >> 23) & 255u) - 127;
      A *= __uint_as_float((u32)(127 - ex) << 23);
      logZ += (float)ex * 0.6931471805599453f;
    }
    if (k < 15) {
#pragma unroll
      for (int m = 0; m < 8; ++m) gc[m] = gn[m];
    }
  }

  float res = logZ + __logf(A);
  res = __shfl(res, 1, 64);           // EOS = 1
  if (j == 0) atomicAdd(out, res);
}

extern "C" void kernel_launch(void* const* d_in, const int* in_sizes, int n_in,
                              void* d_out, int out_size, void* d_ws, size_t ws_size,
                              hipStream_t stream) {
  const float* F     = (const float*)d_in[0];   // features (S,B,D) f32
  const int*   tags  = (const int*)  d_in[1];   // (S,B) i32
  const int*   seq   = (const int*)  d_in[2];   // (B,) i32
  const float* W     = (const float*)d_in[3];   // (T,D) f32
  const float* bias  = (const float*)d_in[4];   // (T,) f32
  const float* trans = (const float*)d_in[5];   // (T,T) f32
  float* out = (float*)d_out;

  char* ws = (char*)d_ws;
  // xbuf : 272 rows x 4096 bf16 (256 used + prefetch slack) @ 0        (2,228,224 B)
  // Wb3  : 128 KiB                                          @ 2228224
  // Ebuf : 16 KiB                                           @ 2359296
  // Gout : 64b x 16k x 64 x 64 bf16 = 8 MiB                 @ 2375680  (ends 10,764,288)
  unsigned short* xbuf = (unsigned short*)ws;
  unsigned short* Wb3  = (unsigned short*)(ws + 2228224);
  u32*            Ebuf = (u32*)(ws + 2359296);
  unsigned short* Gout = (unsigned short*)(ws + 2375680);

  prep       <<<257,  256, 0, stream>>>(W, trans, Wb3, Ebuf, out);
  emit_gemm  <<<256,  256, 0, stream>>>(F, Wb3, bias, xbuf);
  chunk_prod <<<1024, 256, 0, stream>>>(xbuf, trans, Ebuf, tags, seq, Gout, out);
  chain_apply<<<64,    64, 0, stream>>>(xbuf, trans, Gout, seq, out);
}